// Round 2
// baseline (82.828 us; speedup 1.0000x reference)
//
#include <hip/hip_runtime.h>
#include <math.h>

#define NPTS 2048
#define NG 2
#define IMG_H 512
#define IMG_W 512
#define HW (IMG_H * IMG_W)
#define RENDER_SIZE (3 * HW)
// ln(255): sigma above this -> alpha < 1/255 -> contribution exactly zeroed
#define S_MAX 5.5412636f
#define ALPHA_THRESH (1.0f / 255.0f)

#define TW 32   // tile width  (32 px: one 64-lane wave covers 2 rows, 128B-contig writes)
#define TH 8    // tile height
#define TILES_X (IMG_W / TW)
#define TILES_Y (IMG_H / TH)
#define NTILES (TILES_X * TILES_Y)
#define CHUNK_PTS 256

__device__ __forceinline__ float sigmoidf_(float x) {
    return 1.0f / (1.0f + expf(-x));
}

// Single fused kernel: tile-gather render (each pixel written once, final
// clamped value -> no zero-init, no clamp pass, no global atomics) + radii/vis.
__global__ __launch_bounds__(256) void render_kernel(
    const float* __restrict__ xyz, const float* __restrict__ cov2d,
    const float* __restrict__ fdc, const float* __restrict__ opac,
    const float* __restrict__ gfreq, const float* __restrict__ gwts,
    float* __restrict__ out)
{
    __shared__ float s_xn[CHUNK_PTS], s_yn[CHUNK_PTS];
    __shared__ float s_ca[CHUNK_PTS], s_cb[CHUNK_PTS], s_cc[CHUNK_PTS];
    __shared__ float s_op[CHUNK_PTS];
    __shared__ float s_c0[CHUNK_PTS], s_c1[CHUNK_PTS], s_c2[CHUNK_PTS];
    __shared__ float s_fx0[CHUNK_PTS], s_fy0[CHUNK_PTS];
    __shared__ float s_fx1[CHUNK_PTS], s_fy1[CHUNK_PTS];
    __shared__ float s_w0[CHUNK_PTS], s_w1[CHUNK_PTS];
    __shared__ int s_cnt;

    const int t = threadIdx.x;
    const int tile = blockIdx.x;
    const int tx0 = (tile % TILES_X) * TW;
    const int ty0 = (tile / TILES_X) * TH;
    const int ix = tx0 + (t % TW);
    const int iy = ty0 + (t / TW);
    const float pxf = ix + 0.5f;
    const float pyf = iy + 0.5f;

    // ---- radii + visibility (blocks 0..7 cover the 2048 points) ----
    if (tile < NPTS / CHUNK_PTS) {
        int p = tile * CHUNK_PTS + t;
        float sxx = cov2d[p * 3 + 0] + 0.5f;
        float sxy = cov2d[p * 3 + 1];
        float syy = cov2d[p * 3 + 2] + 0.5f;
        // __f*_rn blocks FMA contraction: fp32 rounding must match numpy exactly
        // through ceil() since radii are integer-compared (threshold 0.1).
        float det = __fsub_rn(__fmul_rn(sxx, syy), __fmul_rn(sxy, sxy));
        bool valid = det > 1e-8f;
        float mid = __fmul_rn(0.5f, __fadd_rn(sxx, syy));
        float q = fmaxf(__fsub_rn(__fmul_rn(mid, mid), det), 0.1f);
        float lam = __fadd_rn(mid, sqrtf(q));
        float r = valid ? ceilf(__fmul_rn(3.0f, sqrtf(lam))) : 0.0f;
        out[RENDER_SIZE + p] = r;
        out[RENDER_SIZE + NPTS + p] = (r > 0.0f) ? 1.0f : 0.0f;
    }

    const float txlo = tx0 + 0.5f, txhi = tx0 + (TW - 1) + 0.5f;
    const float tylo = ty0 + 0.5f, tyhi = ty0 + (TH - 1) + 0.5f;

    float acc0 = 0.0f, acc1 = 0.0f, acc2 = 0.0f;

    for (int c = 0; c < NPTS / CHUNK_PTS; ++c) {
        const int p = c * CHUNK_PTS + t;

        // ---- cull: conservative lossless bbox (Schur bound: min sigma along
        // a pixel column/row is dx^2/(2*sxx); beyond sqrt(2*S*sxx) alpha<1/255)
        float sxx = cov2d[p * 3 + 0] + 0.5f;
        float sxy = cov2d[p * 3 + 1];
        float syy = cov2d[p * 3 + 2] + 0.5f;
        float det = sxx * syy - sxy * sxy;
        float xn = xyz[p * 2 + 0];
        float yn = xyz[p * 2 + 1];
        float dxm = sqrtf(2.0f * S_MAX * sxx) + 0.01f;
        float dym = sqrtf(2.0f * S_MAX * syy) + 0.01f;
        bool ok = (det > 1e-8f)
               && (xn - dxm <= txhi) && (xn + dxm >= txlo)
               && (yn - dym <= tyhi) && (yn + dym >= tylo);

        __syncthreads();               // previous chunk done reading s_* / s_cnt
        if (t == 0) s_cnt = 0;
        __syncthreads();

        if (ok) {
            int slot = atomicAdd(&s_cnt, 1);   // LDS atomic, ~5 survivors/tile
            float inv = 1.0f / det;
            s_ca[slot] = syy * inv;
            s_cb[slot] = -sxy * inv;
            s_cc[slot] = sxx * inv;
            s_xn[slot] = xn;
            s_yn[slot] = yn;
            s_op[slot] = opac[p];
            s_c0[slot] = sigmoidf_(fdc[p * 3 + 0]);
            s_c1[slot] = sigmoidf_(fdc[p * 3 + 1]);
            s_c2[slot] = sigmoidf_(fdc[p * 3 + 2]);
            s_fx0[slot] = expf(gfreq[p * 4 + 0]);
            s_fy0[slot] = expf(gfreq[p * 4 + 1]);
            s_fx1[slot] = expf(gfreq[p * 4 + 2]);
            s_fy1[slot] = expf(gfreq[p * 4 + 3]);
            s_w0[slot] = sigmoidf_(gwts[p * 2 + 0]);
            s_w1[slot] = sigmoidf_(gwts[p * 2 + 1]);
        }
        __syncthreads();

        const int n = s_cnt;
        for (int s = 0; s < n; ++s) {   // wave-uniform loop, LDS broadcasts
            float dx = pxf - s_xn[s];
            float dy = pyf - s_yn[s];
            float sigma = 0.5f * (s_ca[s] * dx * dx + s_cc[s] * dy * dy)
                        + s_cb[s] * (dx * dy);
            float alpha = fminf(s_op[s] * expf(-sigma), 0.999f);
            if (alpha >= ALPHA_THRESH) {       // exact reference threshold
                float mod = 1.0f
                    + s_w0[s] * cosf(s_fx0[s] * dx + s_fy0[s] * dy)
                    + s_w1[s] * cosf(s_fx1[s] * dx + s_fy1[s] * dy);
                float wgt = alpha * mod;
                acc0 = fmaf(wgt, s_c0[s], acc0);
                acc1 = fmaf(wgt, s_c1[s], acc1);
                acc2 = fmaf(wgt, s_c2[s], acc2);
            }
        }
    }

    // ---- final clamped write, each pixel exactly once (CHW layout) ----
    const int pix = iy * IMG_W + ix;
    out[pix]          = fminf(fmaxf(acc0, 0.0f), 1.0f);
    out[HW + pix]     = fminf(fmaxf(acc1, 0.0f), 1.0f);
    out[2 * HW + pix] = fminf(fmaxf(acc2, 0.0f), 1.0f);
}

extern "C" void kernel_launch(void* const* d_in, const int* in_sizes, int n_in,
                              void* d_out, int out_size, void* d_ws, size_t ws_size,
                              hipStream_t stream) {
    const float* xyz   = (const float*)d_in[0];
    const float* cov2d = (const float*)d_in[1];
    const float* fdc   = (const float*)d_in[2];
    const float* opac  = (const float*)d_in[3];
    const float* gfreq = (const float*)d_in[4];
    const float* gwts  = (const float*)d_in[5];
    // d_in[6] = background (unused: fully-transparent pixels clamp to 0 anyway
    // per reference: out starts at zeros and background is never composited),
    // d_in[7] = H, d_in[8] = W (compile-time constants here)
    float* out = (float*)d_out;

    render_kernel<<<NTILES, 256, 0, stream>>>(xyz, cov2d, fdc, opac, gfreq, gwts, out);
}